// Round 12
// baseline (229.750 us; speedup 1.0000x reference)
//
#include <hip/hip_runtime.h>
#include <math.h>

// Problem constants (fixed by the reference)
#define HD 512          // Q_DIM = F_DIM = H_DIM = OUT_DIM = 512
#define SP 129          // S+1 = T+1
#define RPAD 144        // padded key rows per batch (129 used, rest zero; 9x16)
#define WPAD 160        // padded weight-vector length (129 used, rest zero)
#define NBATCH 16
#define MQ 4096         // 16*256 query rows
#define SCALE 0.04419417382415922f        // 1/sqrt(512)
#define SCLG2E 0.06375871645788f          // SCALE * log2(e)
#define TANH2E 2.8853900817779268f        // 2 * log2(e)

typedef _Float16 f16;
typedef _Float16 f16x8 __attribute__((ext_vector_type(8)));
typedef _Float16 f16x4 __attribute__((ext_vector_type(4)));
typedef float f32x4  __attribute__((ext_vector_type(4)));

__device__ __forceinline__ void gload_lds16(const f16* g, f16* l) {
  __builtin_amdgcn_global_load_lds(
      (const __attribute__((address_space(1))) void*)g,
      (__attribute__((address_space(3))) void*)l, 16, 0, 0);
}

// ---------------------------------------------------------------------------
// prep: 4 weight transposes (f32 [K][512] -> f16 [512|...][K]) + key pad fill.
// blocks 0..63 Wq, 64..127 Ws, 128..191 Wt, 192..383 Wo, 384..415 pads.
// ---------------------------------------------------------------------------
__global__ __launch_bounds__(256) void prep_kernel(
    const float* __restrict__ Wq, const float* __restrict__ Ws,
    const float* __restrict__ Wt, const float* __restrict__ Wo,
    const float* __restrict__ bs, const float* __restrict__ bt,
    f16* __restrict__ WqT, f16* __restrict__ WsT,
    f16* __restrict__ WtT, f16* __restrict__ WoT,
    f16* __restrict__ skey, f16* __restrict__ tkey,
    f16* __restrict__ skeyT, f16* __restrict__ tkeyT)
{
  const int id = blockIdx.x;
  const int tid = threadIdx.x;
  if (id >= 384) {   // pad fill: key rows 128..143 (row128=bias), keyT cols
    int i = (id - 384) * 256 + tid;    // 16*512
    int b = i >> 9, n = i & 511;
    for (int r = 128; r < RPAD; ++r) {
      skey[((size_t)b*RPAD + r)*HD + n] = (r == 128) ? (f16)bs[n] : (f16)0.f;
      tkey[((size_t)b*RPAD + r)*HD + n] = (r == 128) ? (f16)bt[n] : (f16)0.f;
    }
    size_t o = ((size_t)b*512 + n)*WPAD;
    for (int c = 128; c < WPAD; ++c) {
      skeyT[o + c] = (c == 128) ? (f16)bs[n] : (f16)0.f;
      tkeyT[o + c] = (c == 128) ? (f16)bt[n] : (f16)0.f;
    }
    return;
  }
  const float* W; f16* WT; int K; int rest;
  if (id < 64)       { W = Wq; WT = WqT; K = 512;  rest = id; }
  else if (id < 128) { W = Ws; WT = WsT; K = 512;  rest = id - 64; }
  else if (id < 192) { W = Wt; WT = WtT; K = 512;  rest = id - 128; }
  else               { W = Wo; WT = WoT; K = 1536; rest = id - 192; }
  const int k0 = (rest >> 3) * 64, n0 = (rest & 7) * 64;

  __shared__ float t[64][65];
  const int r = tid >> 4, c4 = (tid & 15) * 4;
  #pragma unroll
  for (int i = 0; i < 4; ++i) {
    int k = r + 16*i;
    float4 v = *(const float4*)(W + (size_t)(k0 + k)*512 + n0 + c4);
    t[k][c4] = v.x; t[k][c4+1] = v.y; t[k][c4+2] = v.z; t[k][c4+3] = v.w;
  }
  __syncthreads();
  #pragma unroll
  for (int i = 0; i < 4; ++i) {
    int n = r + 16*i;
    f16x4 v = { (f16)t[c4][n], (f16)t[c4+1][n], (f16)t[c4+2][n], (f16)t[c4+3][n] };
    *(f16x4*)(WT + (size_t)(n0 + n)*K + k0 + c4) = v;
  }
}

// ---------------------------------------------------------------------------
// Merged input GEMMs (f32 A converted in staging), 64x64 tiles (r7 version):
// x<64: q_h = query@WqT^T+bq ; 64..95: skey(+skeyT) ; 96..127: tkey(+tkeyT)
// ---------------------------------------------------------------------------
__global__ __launch_bounds__(256) void gemm_in(
    const float* __restrict__ query, const float* __restrict__ src,
    const float* __restrict__ trg,
    const f16* __restrict__ WqT, const f16* __restrict__ WsT,
    const f16* __restrict__ WtT,
    const float* __restrict__ bq, const float* __restrict__ bsv,
    const float* __restrict__ btv,
    f16* __restrict__ q_h, f16* __restrict__ skey, f16* __restrict__ tkey,
    f16* __restrict__ skeyT, f16* __restrict__ tkeyT)
{
  __shared__ __align__(16) f16 As[64*64];
  __shared__ __align__(16) f16 Bs[64*64];
  const int x = blockIdx.x;
  const float* A; const f16* WT; const float* bias; int bm; int iskey;
  f16 *Ch, *CT;
  if (x < 64)      { A = query; WT = WqT; bias = bq;  bm = x*64;      iskey = 0; Ch = q_h;  CT = nullptr; }
  else if (x < 96) { A = src;   WT = WsT; bias = bsv; bm = (x-64)*64; iskey = 1; Ch = skey; CT = skeyT; }
  else             { A = trg;   WT = WtT; bias = btv; bm = (x-96)*64; iskey = 1; Ch = tkey; CT = tkeyT; }
  const int bn = blockIdx.y * 64;
  const int tid  = threadIdx.x;
  const int lane = tid & 63;
  const int w    = tid >> 6;
  const int wr   = w & 1, wc = w >> 1;
  const int fq   = lane >> 4, fr = lane & 15;

  f32x4 acc[2][2] = {};

  for (int k0 = 0; k0 < 512; k0 += 64) {
    #pragma unroll
    for (int i = 0; i < 2; ++i) {
      int idx = tid + 256*i;
      int r = idx >> 3, c = idx & 7;
      const float* ap = A + (size_t)(bm + r)*512 + k0 + c*8;
      float4 x0 = *(const float4*)ap;
      float4 x1 = *(const float4*)(ap + 4);
      f16x8 va = { (f16)x0.x, (f16)x0.y, (f16)x0.z, (f16)x0.w,
                   (f16)x1.x, (f16)x1.y, (f16)x1.z, (f16)x1.w };
      const uint4 vb = *(const uint4*)(WT + (size_t)(bn + r)*512 + k0 + c*8);
      int o = ((r << 7) + (c << 4)) ^ ((r & 7) << 4);
      *(f16x8*)((char*)As + o) = va;
      *(uint4*)((char*)Bs + o) = vb;
    }
    __syncthreads();
    #pragma unroll
    for (int ks = 0; ks < 2; ++ks) {
      f16x8 af[2], bf_[2];
      #pragma unroll
      for (int i = 0; i < 2; ++i) {
        int ra = wr*32 + i*16 + fr;
        int oa = ((ra << 7) + (ks << 6) + (fq << 4)) ^ ((ra & 7) << 4);
        af[i] = *(const f16x8*)((const char*)As + oa);
        int rb = wc*32 + i*16 + fr;
        int ob = ((rb << 7) + (ks << 6) + (fq << 4)) ^ ((rb & 7) << 4);
        bf_[i] = *(const f16x8*)((const char*)Bs + ob);
      }
      #pragma unroll
      for (int i = 0; i < 2; ++i)
        #pragma unroll
        for (int j = 0; j < 2; ++j)
          acc[i][j] = __builtin_amdgcn_mfma_f32_16x16x32_f16(af[i], bf_[j], acc[i][j], 0, 0, 0);
    }
    __syncthreads();
  }

  #pragma unroll
  for (int i = 0; i < 2; ++i) {
    #pragma unroll
    for (int j = 0; j < 2; ++j) {
      int n = bn + wc*32 + j*16 + fr;
      float bv = bias[n];
      if (iskey) {
        const int m0 = bm + wr*32 + i*16 + fq*4;
        f16 vals[4];
        #pragma unroll
        for (int r = 0; r < 4; ++r) {
          int m = m0 + r;
          f16 xx = (f16)(acc[i][j][r] + bv);
          vals[r] = xx;
          int mo = (m >> 7) * RPAD + (m & 127);
          Ch[(size_t)mo*512 + n] = xx;
        }
        f16x4 v4 = { vals[0], vals[1], vals[2], vals[3] };
        *(f16x4*)(CT + ((size_t)(m0 >> 7)*512 + n)*WPAD + (m0 & 127)) = v4;
      } else {
        #pragma unroll
        for (int r = 0; r < 4; ++r) {
          int m = bm + wr*32 + i*16 + fq*4 + r;
          Ch[(size_t)m*512 + n] = (f16)(acc[i][j][r] + bv);
        }
      }
    }
  }
}

// ---------------------------------------------------------------------------
// Border scores (raw, f32): Sb[0][l][t] = sum_k q[l,k]*sk128[k]*tk[t,k]
//                           Sb[1][l][s] = sum_k q[l,k]*tk128[k]*sk[s,k]
// grid 256: b(16) x z(2) x mt(4) x jh(2).
// ---------------------------------------------------------------------------
__global__ __launch_bounds__(256) void border_kernel(
    const f16* __restrict__ q_h, const f16* __restrict__ skey,
    const f16* __restrict__ tkey, float* __restrict__ Sb)
{
  const int blk = blockIdx.x;
  const int b  = blk >> 4;
  const int z  = (blk >> 3) & 1;
  const int mt = (blk >> 1) & 3;
  const int jh = blk & 1;
  const int j0 = jh ? 5 : 0;          // tile base
  const int nj = jh ? 4 : 5;          // tiles this block
  const int tasks = nj * 64;          // rows*4 chunks
  const f16* keys = (z ? skey : tkey) + ((size_t)b*RPAD + j0*16)*HD;
  const f16* u    = (z ? tkey : skey) + ((size_t)b*RPAD + 128)*HD;
  const int gid0 = b*256 + mt*64;

  __shared__ __align__(16) f16 Ks[80*32];
  const int tid = threadIdx.x, lane = tid & 63, w = tid >> 6;
  const int fq = lane >> 4, fr = lane & 15;
  const int rslot = (fq ^ ((fr >> 1) & 3)) * 8;           // read slot

  f32x4 acc[5] = {};

  for (int kt = 0; kt < 16; ++kt) {
    uint4 t0, t1;
    {
      int r0 = tid >> 2, c0 = tid & 3;
      t0 = *(const uint4*)(keys + (size_t)r0*HD + kt*32 + c0*8);
      if (tid + 256 < tasks) {
        int r1 = (tid + 256) >> 2;
        t1 = *(const uint4*)(keys + (size_t)r1*HD + kt*32 + c0*8);
      }
    }
    __syncthreads();
    {
      int r0 = tid >> 2, c0 = tid & 3;
      int ws0 = (c0 ^ ((r0 >> 1) & 3)) * 8;
      *(uint4*)(&Ks[r0*32 + ws0]) = t0;
      if (tid + 256 < tasks) {
        int r1 = (tid + 256) >> 2;
        int ws1 = (c0 ^ ((r1 >> 1) & 3)) * 8;
        *(uint4*)(&Ks[r1*32 + ws1]) = t1;
      }
    }
    __syncthreads();
    const f16x8 qf = *(const f16x8*)(q_h + (size_t)(gid0 + w*16 + fr)*HD + kt*32 + fq*8);
    const f16x8 uv = *(const f16x8*)(u + kt*32 + fq*8);
    const f16x8 a = qf * uv;
    #pragma unroll
    for (int j = 0; j < 5; ++j) {
      if (j < nj) {
        const f16x8 bfr = *(const f16x8*)(&Ks[(j*16 + fr)*32 + rslot]);
        acc[j] = __builtin_amdgcn_mfma_f32_16x16x32_f16(a, bfr, acc[j], 0, 0, 0);
      }
    }
  }

  float* dst = Sb + (size_t)z*MQ*RPAD;
  #pragma unroll
  for (int j = 0; j < 5; ++j)
    if (j < nj) {
      #pragma unroll
      for (int r = 0; r < 4; ++r)
        dst[(size_t)(gid0 + w*16 + fq*4 + r)*RPAD + (j0 + j)*16 + fr] = acc[j][r];
    }
}

// ---------------------------------------------------------------------------
// Persistent-keys quadrant attention. Block = (batch, s-half, t-half, rowgrp).
// Both key halves (64 rows x K=512 each) LDS-resident (128 KB, 1 block/CU).
// 4 waves x 16 query rows each, NO barriers in the row loop: per row, q in
// regs, 16 kt x 16 MFMA fed from LDS (chunk-XOR swizzle, rule #21 both-sides).
// Maxless exp (logits bounded ~|8|) -> per-quadrant partial row/col sums.
// ---------------------------------------------------------------------------
__global__ __launch_bounds__(256, 1) void attn_persist(
    const f16* __restrict__ qg,      // (4096, 512)
    const f16* __restrict__ skey,    // (16, 144, 512)
    const f16* __restrict__ tkey,    // (16, 144, 512)
    float* __restrict__ pws,         // (4096, 2[th], 128) partial row sums
    float* __restrict__ pwt)         // (4096, 2[sh], 128) partial col sums
{
  __shared__ __align__(16) f16 KS[64*512];   // 64 KB
  __shared__ __align__(16) f16 KT[64*512];   // 64 KB
  const int tid = threadIdx.x, lane = tid & 63, w = tid >> 6;
  const int fq = lane >> 4, fr = lane & 15;

  // XCD-chunked: 256 blocks -> 32 consecutive per XCD (2 batches' keys per L2)
  const int blk = ((int)blockIdx.x & 7) * 32 + ((int)blockIdx.x >> 3);
  const int b  = blk >> 4;
  const int qd = (blk >> 2) & 3;
  const int sh = qd >> 1, th = qd & 1;
  const int rg = blk & 3;
  const f16* skg = skey + ((size_t)b*RPAD + sh*64)*HD;
  const f16* tkg = tkey + ((size_t)b*RPAD + th*64)*HD;

  // one-time stage: 128 rows (1KB each = one gload per row), source-swizzled
  // so LDS chunk p of row r holds global chunk (p&56)|((p&7)^(r&7)).
  const int lgrp = (lane >> 3) * 8;
  const int llow = lane & 7;
  for (int n = 0; n < 32; ++n) {
    int idx = w*32 + n;
    int key = idx >> 6;
    int r = idx & 63;
    const f16* gb = key ? tkg : skg;
    const f16* g = gb + (size_t)r*HD + (lgrp + (llow ^ (r & 7)))*8;
    f16* l = (key ? KT : KS) + r*512;
    gload_lds16(g, l);
  }
  asm volatile("s_waitcnt vmcnt(0)" ::: "memory");
  __syncthreads();

  for (int rr = 0; rr < 16; ++rr) {
    const int gid = b*256 + rg*64 + w*16 + rr;
    const f16* qrow = qg + (size_t)gid*HD;
    f16x8 qbuf[16];
    #pragma unroll
    for (int kt = 0; kt < 16; ++kt)
      qbuf[kt] = *(const f16x8*)(qrow + kt*32 + fq*8);

    f32x4 acc[4][4] = {};
    #pragma unroll
    for (int kt = 0; kt < 16; ++kt) {
      const int cbase = kt*4 + fq;          // global chunk index
      const int cgrp  = cbase & 56;
      const int clow  = cbase & 7;
      f16x8 B[4];
      #pragma unroll
      for (int j = 0; j < 4; ++j) {
        int rt = j*16 + fr;
        int p = cgrp | (clow ^ (rt & 7));
        B[j] = *(const f16x8*)(KT + rt*512 + p*8);
      }
      __builtin_amdgcn_s_setprio(1);
      #pragma unroll
      for (int i = 0; i < 4; ++i) {
        int rs = i*16 + fr;
        int p = cgrp | (clow ^ (rs & 7));
        const f16x8 raw = *(const f16x8*)(KS + rs*512 + p*8);
        const f16x8 a = raw * qbuf[kt];     // v_pk_mul_f16
        #pragma unroll
        for (int j = 0; j < 4; ++j)
          acc[i][j] = __builtin_amdgcn_mfma_f32_16x16x32_f16(a, B[j], acc[i][j], 0, 0, 0);
      }
      __builtin_amdgcn_s_setprio(0);
    }

    // maxless exp (logits bounded; f32 range safe)
    #pragma unroll
    for (int i = 0; i < 4; ++i)
      #pragma unroll
      for (int j = 0; j < 4; ++j)
        #pragma unroll
        for (int r = 0; r < 4; ++r)
          acc[i][j][r] = exp2f(acc[i][j][r] * SCLG2E);

    // partial row sums (this t-half) -> pws[gid][th][sh*64 + s]
    #pragma unroll
    for (int i = 0; i < 4; ++i) {
      #pragma unroll
      for (int r = 0; r < 4; ++r) {
        float rs = acc[i][0][r] + acc[i][1][r] + acc[i][2][r] + acc[i][3][r];
        rs += __shfl_xor(rs, 1); rs += __shfl_xor(rs, 2);
        rs += __shfl_xor(rs, 4); rs += __shfl_xor(rs, 8);
        if (fr == 0)
          pws[((size_t)gid*2 + th)*128 + sh*64 + i*16 + fq*4 + r] = rs;
      }
    }
    // partial col sums (this s-half) -> pwt[gid][sh][th*64 + t]
    #pragma unroll
    for (int j = 0; j < 4; ++j) {
      float cs = 0.f;
      #pragma unroll
      for (int i = 0; i < 4; ++i)
        #pragma unroll
        for (int r = 0; r < 4; ++r) cs += acc[i][j][r];
      cs += __shfl_xor(cs, 16); cs += __shfl_xor(cs, 32);
      if (fq == 0)
        pwt[((size_t)gid*2 + sh)*128 + th*64 + j*16 + fr] = cs;
    }
  }
}

// ---------------------------------------------------------------------------
// Combine: merge quadrant partials + borders -> normalized weights wsn/wtn.
// grid 256 x 16 rows each.
// ---------------------------------------------------------------------------
__global__ __launch_bounds__(256) void combine_kernel(
    const float* __restrict__ pws, const float* __restrict__ pwt,
    const float* __restrict__ Sb,
    f16* __restrict__ wsn, f16* __restrict__ wtn)
{
  __shared__ float redZ[4], redT[4], redS[4];
  __shared__ float cornerP;
  const int tid = threadIdx.x, lane = tid & 63, w = tid >> 6;

  for (int rr = 0; rr < 16; ++rr) {
    const int gid = blockIdx.x * 16 + rr;
    const float* SbT = Sb + (size_t)gid*RPAD;
    const float* SbS = Sb + (size_t)MQ*RPAD + (size_t)gid*RPAD;
    const float pbt = (tid < 129) ? exp2f(SbT[tid]*SCLG2E) : 0.f;
    const float pbs = (tid < 128) ? exp2f(SbS[tid]*SCLG2E) : 0.f;
    float wsc = 0.f, wtc = 0.f;
    if (tid < 128) {
      wsc = pws[((size_t)gid*2 + 0)*128 + tid] + pws[((size_t)gid*2 + 1)*128 + tid];
      wtc = pwt[((size_t)gid*2 + 0)*128 + tid] + pwt[((size_t)gid*2 + 1)*128 + tid];
    }
    float zc = wsc, zt = pbt, zs = pbs;
    #pragma unroll
    for (int off = 32; off > 0; off >>= 1) {
      zc += __shfl_xor(zc, off);
      zt += __shfl_xor(zt, off);
      zs += __shfl_xor(zs, off);
    }
    if (lane == 0) { redZ[w] = zc; redT[w] = zt; redS[w] = zs; }
    if (tid == 128) cornerP = pbt;
    __syncthreads();
    const float wsc_sum = redZ[0] + redZ[1] + redZ[2] + redZ[3];
    const float pbt_sum = redT[0] + redT[1] + redT[2] + redT[3];
    const float pbs_sum = redS[0] + redS[1] + redS[2] + redS[3];
    const float invZ = 1.0f / (wsc_sum + pbt_sum + pbs_sum);
    if (tid < WPAD) {
      float wsv = (tid < 128) ? (wsc + pbs) : (tid == 128) ? pbt_sum : 0.f;
      float wtv = (tid < 128) ? (wtc + pbt) : (tid == 128) ? (pbs_sum + cornerP) : 0.f;
      wsn[(size_t)gid*WPAD + tid] = (f16)(wsv * invZ);
      wtn[(size_t)gid*WPAD + tid] = (f16)(wtv * invZ);
    }
    __syncthreads();
  }
}

// ---------------------------------------------------------------------------
// ctx GEMM: sctx[l][hd] = sum_s wsn[l][s] * skey[s][hd]  (keyT pre-transposed)
// ---------------------------------------------------------------------------
__global__ __launch_bounds__(256) void ctx_gemm(
    const f16* __restrict__ wsn, const f16* __restrict__ wtn,
    const f16* __restrict__ skeyT, const f16* __restrict__ tkeyT,
    f16* __restrict__ sctx, f16* __restrict__ tctx)
{
  __shared__ __align__(16) f16 As[64*168];
  __shared__ __align__(16) f16 Bs[64*168];
  const int z = blockIdx.x & 1, b = blockIdx.x >> 1;
  const int mt = blockIdx.y, nt = blockIdx.z;
  const int tid = threadIdx.x, lane = tid & 63, w = tid >> 6;
  const int wr = w & 1, wc = w >> 1;
  const int fq = lane >> 4, fr = lane & 15;

  const f16* A  = (z ? wtn : wsn) + ((size_t)b*256 + mt*64)*WPAD;
  const f16* Bt = (z ? tkeyT : skeyT) + ((size_t)b*512 + nt*64)*WPAD;

  for (int t = tid; t < 1280; t += 256) {
    int r = t / 20, c = t % 20;
    *(uint4*)(&As[r*168 + c*8]) = *(const uint4*)(A + (size_t)r*WPAD + c*8);
    *(uint4*)(&Bs[r*168 + c*8]) = *(const uint4*)(Bt + (size_t)r*WPAD + c*8);
  }
  __syncthreads();

  f32x4 acc[2][2] = {};
  #pragma unroll
  for (int ks = 0; ks < 5; ++ks) {
    f16x8 af[2], bf_[2];
    #pragma unroll
    for (int i = 0; i < 2; ++i) {
      af[i]  = *(const f16x8*)(&As[(wr*32 + i*16 + fr)*168 + ks*32 + fq*8]);
      bf_[i] = *(const f16x8*)(&Bs[(wc*32 + i*16 + fr)*168 + ks*32 + fq*8]);
    }
    #pragma unroll
    for (int i = 0; i < 2; ++i)
      #pragma unroll
      for (int j = 0; j < 2; ++j)
        acc[i][j] = __builtin_amdgcn_mfma_f32_16x16x32_f16(af[i], bf_[j], acc[i][j], 0, 0, 0);
  }

  f16* out = z ? tctx : sctx;
  #pragma unroll
  for (int i = 0; i < 2; ++i)
    #pragma unroll
    for (int j = 0; j < 2; ++j) {
      int col = nt*64 + wc*32 + j*16 + fr;
      #pragma unroll
      for (int r = 0; r < 4; ++r) {
        int row = b*256 + mt*64 + wr*32 + i*16 + fq*4 + r;
        out[(size_t)row*HD + col] = (f16)acc[i][j][r];
      }
    }
}

// ---------------------------------------------------------------------------
// out = tanh([query(f32) | sctx | tctx] @ WoT^T + bo), K = 1536, f32 out.
// ---------------------------------------------------------------------------
__global__ __launch_bounds__(256) void gemm_out(
    const float* __restrict__ query, const f16* __restrict__ sctx,
    const f16* __restrict__ tctx, const f16* __restrict__ WoT,
    const float* __restrict__ bias, float* __restrict__ C)
{
  __shared__ __align__(16) f16 As[64*64];
  __shared__ __align__(16) f16 Bs[64*64];
  const int tid  = threadIdx.x;
  const int lane = tid & 63;
  const int w    = tid >> 6;
  const int wr   = w & 1, wc = w >> 1;
  const int fq   = lane >> 4, fr = lane & 15;
  const int bm = blockIdx.x * 64, bn = blockIdx.y * 64;

  f32x4 acc[2][2] = {};

  for (int k0 = 0; k0 < 1536; k0 += 64) {
    const int seg  = k0 >> 9;
    const int kloc = k0 & 511;
    #pragma unroll
    for (int i = 0; i < 2; ++i) {
      int idx = tid + 256*i;
      int r = idx >> 3, c = idx & 7;
      int o = ((r << 7) + (c << 4)) ^ ((r & 7) << 4);
      if (seg == 0) {
        const float* ap = query + (size_t)(bm + r)*512 + kloc + c*8;
        float4 x0 = *(const float4*)ap;
        float4 x1 = *(const float4*)(ap + 4);
        f16x8 va = { (f16)x0.x, (f16)x0.y, (f16)x0.z, (f16)x0.w,
                     (f16)x1.x, (f16)x1.y, (f16)x1.z, (f16)x1.w };
        *(f16x8*)((char*)As + o) = va;
      } else {
        const f16* Ap = (seg == 1) ? sctx : tctx;
        *(uint4*)((char*)As + o) = *(const uint4*)(Ap + (size_t)(bm + r)*512 + kloc + c*8);
      }
      *(uint4*)((char*)Bs + o) = *(const uint4*)(WoT + (size_t)(bn + r)*1536 + k0 + c*8);
    }
    __syncthreads();
    #pragma unroll
    for (int ks = 0; ks < 2; ++ks) {
      f16x8 af[2], bf_[2];
      #pragma unroll
      for (int i = 0; i < 2; ++i) {
        int ra = wr*32 + i*16 + fr;
        int oa = ((ra << 7) + (ks << 6) + (fq << 4)) ^ ((ra & 7) << 4);
        af[i] = *(const f16x8*)((const char*)As + oa);
        int rb = wc*32 + i*16 + fr;
        int ob = ((rb << 7) + (ks << 6) + (fq << 4)) ^ ((rb & 7) << 4);
        bf_[i] = *(const f16x8*)((const char*)Bs + ob);
      }
      #pragma unroll
      for (int i = 0; i < 2; ++i)
        #pragma unroll
        for (int j = 0; j < 2; ++j)
          acc[i][j] = __builtin_amdgcn_mfma_f32_16x16x32_f16(af[i], bf_[j], acc[i][j], 0, 0, 0);
    }
    __syncthreads();
  }

  #pragma unroll
  for (int i = 0; i < 2; ++i)
    #pragma unroll
    for (int j = 0; j < 2; ++j) {
      int n = bn + wc*32 + j*16 + fr;
      float bv = bias[n];
      #pragma unroll
      for (int r = 0; r < 4; ++r) {
        int m = bm + wr*32 + i*16 + fq*4 + r;
        float xx = acc[i][j][r] + bv;
        xx = fminf(fmaxf(xx, -20.f), 20.f);
        float e = exp2f(TANH2E * xx);
        C[(size_t)m*HD + n] = (e - 1.0f) / (e + 1.0f);
      }
    }
}

extern "C" void kernel_launch(void* const* d_in, const int* in_sizes, int n_in,
                              void* d_out, int out_size, void* d_ws, size_t ws_size,
                              hipStream_t stream) {
  (void)in_sizes; (void)n_in; (void)out_size; (void)ws_size;
  const float* query = (const float*)d_in[0];
  const float* src   = (const float*)d_in[1];
  const float* trg   = (const float*)d_in[2];
  const float* Wq    = (const float*)d_in[3];
  const float* bq    = (const float*)d_in[4];
  const float* Wsm   = (const float*)d_in[5];
  const float* bs    = (const float*)d_in[6];
  const float* Wtm   = (const float*)d_in[7];
  const float* bt    = (const float*)d_in[8];
  const float* Wo    = (const float*)d_in[9];
  const float* bo    = (const float*)d_in[10];
  float* out = (float*)d_out;

  // workspace layout (~32 MB); pws/pwt (4 MB each) alias sctx/tctx: partials
  // are fully consumed by combine_kernel before ctx_gemm writes sctx/tctx.
  char* p = (char*)d_ws;
  f16* WqT   = (f16*)p;  p += (size_t)HD*HD*2;
  f16* WsT   = (f16*)p;  p += (size_t)HD*HD*2;
  f16* WtT   = (f16*)p;  p += (size_t)HD*HD*2;
  f16* WoT   = (f16*)p;  p += (size_t)1536*HD*2;
  f16* q_h   = (f16*)p;  p += (size_t)MQ*HD*2;
  f16* skey  = (f16*)p;  p += (size_t)NBATCH*RPAD*HD*2;
  f16* tkey  = (f16*)p;  p += (size_t)NBATCH*RPAD*HD*2;
  f16* skeyT = (f16*)p;  p += (size_t)NBATCH*HD*WPAD*2;
  f16* tkeyT = (f16*)p;  p += (size_t)NBATCH*HD*WPAD*2;
  f16* wsn   = (f16*)p;  p += (size_t)MQ*WPAD*2;
  f16* wtn   = (f16*)p;  p += (size_t)MQ*WPAD*2;
  f16* sctx  = (f16*)p;  p += (size_t)MQ*HD*2;
  f16* tctx  = (f16*)p;  p += (size_t)MQ*HD*2;
  float* Sb  = (float*)p; p += (size_t)2*MQ*RPAD*4;
  float* pws = (float*)sctx;   // 4096*2*128*4 = 4 MB alias
  float* pwt = (float*)tctx;   // 4 MB alias

  dim3 blk(256);
  prep_kernel<<<dim3(416), blk, 0, stream>>>(Wq, Wsm, Wtm, Wo, bs, bt,
                                             WqT, WsT, WtT, WoT,
                                             skey, tkey, skeyT, tkeyT);
  gemm_in<<<dim3(128, 8), blk, 0, stream>>>(query, src, trg, WqT, WsT, WtT,
                                            bq, bs, bt, q_h, skey, tkey,
                                            skeyT, tkeyT);
  border_kernel<<<dim3(256), blk, 0, stream>>>(q_h, skey, tkey, Sb);
  attn_persist<<<dim3(256), blk, 0, stream>>>(q_h, skey, tkey, pws, pwt);
  combine_kernel<<<dim3(256), blk, 0, stream>>>(pws, pwt, Sb, wsn, wtn);
  ctx_gemm<<<dim3(32, 4, 8), blk, 0, stream>>>(wsn, wtn, skeyT, tkeyT, sctx, tctx);
  gemm_out<<<dim3(64, 8), blk, 0, stream>>>(query, sctx, tctx, WoT, bo, out);
}

// Round 13
// 192.177 us; speedup vs baseline: 1.1955x; 1.1955x over previous
//
#include <hip/hip_runtime.h>
#include <math.h>

// Problem constants (fixed by the reference)
#define HD 512          // Q_DIM = F_DIM = H_DIM = OUT_DIM = 512
#define SP 129          // S+1 = T+1
#define RPAD 144        // padded key rows per batch (129 used, rest zero; 9x16)
#define WPAD 160        // padded weight-vector length (129 used, rest zero)
#define NBATCH 16
#define MQ 4096         // 16*256 query rows
#define SCALE 0.04419417382415922f        // 1/sqrt(512)
#define SCLG2E 0.06375871645788f          // SCALE * log2(e)
#define TANH2E 2.8853900817779268f        // 2 * log2(e)

typedef _Float16 f16;
typedef _Float16 f16x8 __attribute__((ext_vector_type(8)));
typedef _Float16 f16x4 __attribute__((ext_vector_type(4)));
typedef float f32x4  __attribute__((ext_vector_type(4)));

__device__ __forceinline__ void gload_lds16(const f16* g, f16* l) {
  __builtin_amdgcn_global_load_lds(
      (const __attribute__((address_space(1))) void*)g,
      (__attribute__((address_space(3))) void*)l, 16, 0, 0);
}

// ---------------------------------------------------------------------------
// prep: 4 weight transposes (f32 [K][512] -> f16 [512|...][K]) + key pad fill.
// blocks 0..63 Wq, 64..127 Ws, 128..191 Wt, 192..383 Wo, 384..415 pads.
// ---------------------------------------------------------------------------
__global__ __launch_bounds__(256) void prep_kernel(
    const float* __restrict__ Wq, const float* __restrict__ Ws,
    const float* __restrict__ Wt, const float* __restrict__ Wo,
    const float* __restrict__ bs, const float* __restrict__ bt,
    f16* __restrict__ WqT, f16* __restrict__ WsT,
    f16* __restrict__ WtT, f16* __restrict__ WoT,
    f16* __restrict__ skey, f16* __restrict__ tkey,
    f16* __restrict__ skeyT, f16* __restrict__ tkeyT)
{
  const int id = blockIdx.x;
  const int tid = threadIdx.x;
  if (id >= 384) {   // pad fill: key rows 128..143 (row128=bias), keyT cols
    int i = (id - 384) * 256 + tid;    // 16*512
    int b = i >> 9, n = i & 511;
    for (int r = 128; r < RPAD; ++r) {
      skey[((size_t)b*RPAD + r)*HD + n] = (r == 128) ? (f16)bs[n] : (f16)0.f;
      tkey[((size_t)b*RPAD + r)*HD + n] = (r == 128) ? (f16)bt[n] : (f16)0.f;
    }
    size_t o = ((size_t)b*512 + n)*WPAD;
    for (int c = 128; c < WPAD; ++c) {
      skeyT[o + c] = (c == 128) ? (f16)bs[n] : (f16)0.f;
      tkeyT[o + c] = (c == 128) ? (f16)bt[n] : (f16)0.f;
    }
    return;
  }
  const float* W; f16* WT; int K; int rest;
  if (id < 64)       { W = Wq; WT = WqT; K = 512;  rest = id; }
  else if (id < 128) { W = Ws; WT = WsT; K = 512;  rest = id - 64; }
  else if (id < 192) { W = Wt; WT = WtT; K = 512;  rest = id - 128; }
  else               { W = Wo; WT = WoT; K = 1536; rest = id - 192; }
  const int k0 = (rest >> 3) * 64, n0 = (rest & 7) * 64;

  __shared__ float t[64][65];
  const int r = tid >> 4, c4 = (tid & 15) * 4;
  #pragma unroll
  for (int i = 0; i < 4; ++i) {
    int k = r + 16*i;
    float4 v = *(const float4*)(W + (size_t)(k0 + k)*512 + n0 + c4);
    t[k][c4] = v.x; t[k][c4+1] = v.y; t[k][c4+2] = v.z; t[k][c4+3] = v.w;
  }
  __syncthreads();
  #pragma unroll
  for (int i = 0; i < 4; ++i) {
    int n = r + 16*i;
    f16x4 v = { (f16)t[c4][n], (f16)t[c4+1][n], (f16)t[c4+2][n], (f16)t[c4+3][n] };
    *(f16x4*)(WT + (size_t)(n0 + n)*K + k0 + c4) = v;
  }
}

// ---------------------------------------------------------------------------
// Merged input GEMMs (f32 A converted in staging), 64x64 tiles (r7 version):
// x<64: q_h = query@WqT^T+bq ; 64..95: skey(+skeyT) ; 96..127: tkey(+tkeyT)
// ---------------------------------------------------------------------------
__global__ __launch_bounds__(256) void gemm_in(
    const float* __restrict__ query, const float* __restrict__ src,
    const float* __restrict__ trg,
    const f16* __restrict__ WqT, const f16* __restrict__ WsT,
    const f16* __restrict__ WtT,
    const float* __restrict__ bq, const float* __restrict__ bsv,
    const float* __restrict__ btv,
    f16* __restrict__ q_h, f16* __restrict__ skey, f16* __restrict__ tkey,
    f16* __restrict__ skeyT, f16* __restrict__ tkeyT)
{
  __shared__ __align__(16) f16 As[64*64];
  __shared__ __align__(16) f16 Bs[64*64];
  const int x = blockIdx.x;
  const float* A; const f16* WT; const float* bias; int bm; int iskey;
  f16 *Ch, *CT;
  if (x < 64)      { A = query; WT = WqT; bias = bq;  bm = x*64;      iskey = 0; Ch = q_h;  CT = nullptr; }
  else if (x < 96) { A = src;   WT = WsT; bias = bsv; bm = (x-64)*64; iskey = 1; Ch = skey; CT = skeyT; }
  else             { A = trg;   WT = WtT; bias = btv; bm = (x-96)*64; iskey = 1; Ch = tkey; CT = tkeyT; }
  const int bn = blockIdx.y * 64;
  const int tid  = threadIdx.x;
  const int lane = tid & 63;
  const int w    = tid >> 6;
  const int wr   = w & 1, wc = w >> 1;
  const int fq   = lane >> 4, fr = lane & 15;

  f32x4 acc[2][2] = {};

  for (int k0 = 0; k0 < 512; k0 += 64) {
    #pragma unroll
    for (int i = 0; i < 2; ++i) {
      int idx = tid + 256*i;
      int r = idx >> 3, c = idx & 7;
      const float* ap = A + (size_t)(bm + r)*512 + k0 + c*8;
      float4 x0 = *(const float4*)ap;
      float4 x1 = *(const float4*)(ap + 4);
      f16x8 va = { (f16)x0.x, (f16)x0.y, (f16)x0.z, (f16)x0.w,
                   (f16)x1.x, (f16)x1.y, (f16)x1.z, (f16)x1.w };
      const uint4 vb = *(const uint4*)(WT + (size_t)(bn + r)*512 + k0 + c*8);
      int o = ((r << 7) + (c << 4)) ^ ((r & 7) << 4);
      *(f16x8*)((char*)As + o) = va;
      *(uint4*)((char*)Bs + o) = vb;
    }
    __syncthreads();
    #pragma unroll
    for (int ks = 0; ks < 2; ++ks) {
      f16x8 af[2], bf_[2];
      #pragma unroll
      for (int i = 0; i < 2; ++i) {
        int ra = wr*32 + i*16 + fr;
        int oa = ((ra << 7) + (ks << 6) + (fq << 4)) ^ ((ra & 7) << 4);
        af[i] = *(const f16x8*)((const char*)As + oa);
        int rb = wc*32 + i*16 + fr;
        int ob = ((rb << 7) + (ks << 6) + (fq << 4)) ^ ((rb & 7) << 4);
        bf_[i] = *(const f16x8*)((const char*)Bs + ob);
      }
      #pragma unroll
      for (int i = 0; i < 2; ++i)
        #pragma unroll
        for (int j = 0; j < 2; ++j)
          acc[i][j] = __builtin_amdgcn_mfma_f32_16x16x32_f16(af[i], bf_[j], acc[i][j], 0, 0, 0);
    }
    __syncthreads();
  }

  #pragma unroll
  for (int i = 0; i < 2; ++i) {
    #pragma unroll
    for (int j = 0; j < 2; ++j) {
      int n = bn + wc*32 + j*16 + fr;
      float bv = bias[n];
      if (iskey) {
        const int m0 = bm + wr*32 + i*16 + fq*4;
        f16 vals[4];
        #pragma unroll
        for (int r = 0; r < 4; ++r) {
          int m = m0 + r;
          f16 xx = (f16)(acc[i][j][r] + bv);
          vals[r] = xx;
          int mo = (m >> 7) * RPAD + (m & 127);
          Ch[(size_t)mo*512 + n] = xx;
        }
        f16x4 v4 = { vals[0], vals[1], vals[2], vals[3] };
        *(f16x4*)(CT + ((size_t)(m0 >> 7)*512 + n)*WPAD + (m0 & 127)) = v4;
      } else {
        #pragma unroll
        for (int r = 0; r < 4; ++r) {
          int m = bm + wr*32 + i*16 + fq*4 + r;
          Ch[(size_t)m*512 + n] = (f16)(acc[i][j][r] + bv);
        }
      }
    }
  }
}

// ---------------------------------------------------------------------------
// Border scores (raw, f32): Sb[0][l][t] = sum_k q[l,k]*sk128[k]*tk[t,k]
//                           Sb[1][l][s] = sum_k q[l,k]*tk128[k]*sk[s,k]
// grid 256: b(16) x z(2) x mt(4) x jh(2).
// ---------------------------------------------------------------------------
__global__ __launch_bounds__(256) void border_kernel(
    const f16* __restrict__ q_h, const f16* __restrict__ skey,
    const f16* __restrict__ tkey, float* __restrict__ Sb)
{
  const int blk = blockIdx.x;
  const int b  = blk >> 4;
  const int z  = (blk >> 3) & 1;
  const int mt = (blk >> 1) & 3;
  const int jh = blk & 1;
  const int j0 = jh ? 5 : 0;          // tile base
  const int nj = jh ? 4 : 5;          // tiles this block
  const int tasks = nj * 64;          // rows*4 chunks
  const f16* keys = (z ? skey : tkey) + ((size_t)b*RPAD + j0*16)*HD;
  const f16* u    = (z ? tkey : skey) + ((size_t)b*RPAD + 128)*HD;
  const int gid0 = b*256 + mt*64;

  __shared__ __align__(16) f16 Ks[80*32];
  const int tid = threadIdx.x, lane = tid & 63, w = tid >> 6;
  const int fq = lane >> 4, fr = lane & 15;
  const int rslot = (fq ^ ((fr >> 1) & 3)) * 8;           // read slot

  f32x4 acc[5] = {};

  for (int kt = 0; kt < 16; ++kt) {
    uint4 t0, t1;
    {
      int r0 = tid >> 2, c0 = tid & 3;
      t0 = *(const uint4*)(keys + (size_t)r0*HD + kt*32 + c0*8);
      if (tid + 256 < tasks) {
        int r1 = (tid + 256) >> 2;
        t1 = *(const uint4*)(keys + (size_t)r1*HD + kt*32 + c0*8);
      }
    }
    __syncthreads();
    {
      int r0 = tid >> 2, c0 = tid & 3;
      int ws0 = (c0 ^ ((r0 >> 1) & 3)) * 8;
      *(uint4*)(&Ks[r0*32 + ws0]) = t0;
      if (tid + 256 < tasks) {
        int r1 = (tid + 256) >> 2;
        int ws1 = (c0 ^ ((r1 >> 1) & 3)) * 8;
        *(uint4*)(&Ks[r1*32 + ws1]) = t1;
      }
    }
    __syncthreads();
    const f16x8 qf = *(const f16x8*)(q_h + (size_t)(gid0 + w*16 + fr)*HD + kt*32 + fq*8);
    const f16x8 uv = *(const f16x8*)(u + kt*32 + fq*8);
    const f16x8 a = qf * uv;
    #pragma unroll
    for (int j = 0; j < 5; ++j) {
      if (j < nj) {
        const f16x8 bfr = *(const f16x8*)(&Ks[(j*16 + fr)*32 + rslot]);
        acc[j] = __builtin_amdgcn_mfma_f32_16x16x32_f16(a, bfr, acc[j], 0, 0, 0);
      }
    }
  }

  float* dst = Sb + (size_t)z*MQ*RPAD;
  #pragma unroll
  for (int j = 0; j < 5; ++j)
    if (j < nj) {
      #pragma unroll
      for (int r = 0; r < 4; ++r)
        dst[(size_t)(gid0 + w*16 + fq*4 + r)*RPAD + (j0 + j)*16 + fr] = acc[j][r];
    }
}

// ---------------------------------------------------------------------------
// Core trilinear attention: 1 query row / block, 4 waves, 128x128 core only.
// (best-measured version: 116 us, 4 blocks/CU, conflict-free swizzle)
// ---------------------------------------------------------------------------
__global__ __launch_bounds__(256, 4) void attn_core(
    const f16* __restrict__ qg,      // (4096, 512)
    const f16* __restrict__ skey,    // (16, 144, 512)
    const f16* __restrict__ tkey,    // (16, 144, 512)
    const float* __restrict__ Sb,    // (2, 4096, 144) raw border scores
    f16* __restrict__ wsn,           // (4096, 160) normalized row weights
    f16* __restrict__ wtn)           // (4096, 160) normalized col weights
{
  __shared__ __align__(16) f16 KB[2*2*128*32];   // 32 KB
  __shared__ __align__(16) f16 qs[HD];
  __shared__ float wsA[2][128];
  __shared__ float wtA[2][128];
  __shared__ float redA[4], redB[4], redC[4], redD[4], redE[4];
  __shared__ float cornerP;

  const int tid  = threadIdx.x;
  const int lane = tid & 63;
  const int w    = tid >> 6;
  const int rb   = w & 1;    // row half (s tiles 0..3 / 4..7)
  const int cb   = w >> 1;   // col half
  const int fq   = lane >> 4;
  const int fr   = lane & 15;
  const int so   = (fq ^ ((fr >> 1) & 3)) << 3;   // read slot
  const int gc   = ((lane & 3) ^ ((lane >> 3) & 3)) * 8;  // staged global chunk

  // XCD-chunked swizzle: 4096 blocks -> 512 consecutive rows per XCD
  const int gid = ((int)blockIdx.x & 7) * 512 + ((int)blockIdx.x >> 3);
  const int b   = gid >> 8;
  const f16* skg = skey + (size_t)b * RPAD * HD;
  const f16* tkg = tkey + (size_t)b * RPAD * HD;

  if (tid < 64) *(uint4*)(qs + tid*8) = *(const uint4*)(qg + (size_t)gid*HD + tid*8);

  auto stage = [&](int kt, int buf) {
    #pragma unroll
    for (int n = 0; n < 4; ++n) {
      int idx = w*4 + n;             // 0..15
      int key = idx >> 3;
      int rg  = idx & 7;             // 16-row group
      const f16* g = (key ? tkg : skg)
                   + (size_t)(rg*16 + (lane >> 2))*HD + kt*32 + gc;
      f16* l = &KB[((buf*2 + key)*128 + rg*16)*32];
      gload_lds16(g, l);
    }
  };

  f32x4 acc[4][4] = {};

  auto mfma_kt = [&](int kt, int cur) {
    const f16x8 qv = *(const f16x8*)(&qs[kt*32 + fq*8]);
    const int abase = (cur*2 + 0)*128*32;
    const int bbase = (cur*2 + 1)*128*32;
    f16x8 B[4];
    #pragma unroll
    for (int j = 0; j < 4; ++j) {
      int rt = cb*64 + j*16 + fr;
      B[j] = *(const f16x8*)(&KB[bbase + rt*32 + so]);
    }
    __builtin_amdgcn_s_setprio(1);
    #pragma unroll
    for (int i = 0; i < 4; ++i) {
      int rs = rb*64 + i*16 + fr;
      const f16x8 raw = *(const f16x8*)(&KB[abase + rs*32 + so]);
      const f16x8 a = raw * qv;      // v_pk_mul_f16
      #pragma unroll
      for (int j = 0; j < 4; ++j)
        acc[i][j] = __builtin_amdgcn_mfma_f32_16x16x32_f16(a, B[j], acc[i][j], 0, 0, 0);
    }
    __builtin_amdgcn_s_setprio(0);
  };

  stage(0, 0);
  __syncthreads();                    // drains vmcnt(0); qs visible

  for (int kt = 0; kt < 16; ++kt) {
    const int cur = kt & 1;
    if (kt < 15) {
      stage(kt + 1, cur ^ 1);
      asm volatile("s_waitcnt vmcnt(4)" ::: "memory");   // prev tile landed
    } else {
      asm volatile("s_waitcnt vmcnt(0)" ::: "memory");
    }
    __builtin_amdgcn_s_barrier();
    mfma_kt(kt, cur);
    __builtin_amdgcn_s_barrier();
  }

  // ---- max: core (regs) + border (global) ----
  float m = -3e38f;
  #pragma unroll
  for (int i = 0; i < 4; ++i)
    #pragma unroll
    for (int j = 0; j < 4; ++j)
      #pragma unroll
      for (int r = 0; r < 4; ++r) m = fmaxf(m, acc[i][j][r]);
  #pragma unroll
  for (int off = 32; off > 0; off >>= 1) m = fmaxf(m, __shfl_xor(m, off));
  if (lane == 0) redA[w] = m;

  const float* SbT = Sb + (size_t)gid*RPAD;
  const float* SbS = Sb + (size_t)MQ*RPAD + (size_t)gid*RPAD;
  const float btv = (tid < 129) ? SbT[tid] : -3e38f;
  const float bsv = (tid < 128) ? SbS[tid] : -3e38f;
  float bm = fmaxf(btv, bsv);
  #pragma unroll
  for (int off = 32; off > 0; off >>= 1) bm = fmaxf(bm, __shfl_xor(bm, off));
  if (lane == 0) redB[w] = bm;
  __syncthreads();
  const float mraw = fmaxf(
      fmaxf(fmaxf(redA[0], redA[1]), fmaxf(redA[2], redA[3])),
      fmaxf(fmaxf(redB[0], redB[1]), fmaxf(redB[2], redB[3])));

  // ---- exp core + core sum (exp2 with folded constant) ----
  float csum = 0.f;
  #pragma unroll
  for (int i = 0; i < 4; ++i)
    #pragma unroll
    for (int j = 0; j < 4; ++j)
      #pragma unroll
      for (int r = 0; r < 4; ++r) {
        float p = exp2f((acc[i][j][r] - mraw) * SCLG2E);
        acc[i][j][r] = p;
        csum += p;
      }
  #pragma unroll
  for (int off = 32; off > 0; off >>= 1) csum += __shfl_xor(csum, off);
  if (lane == 0) redC[w] = csum;

  // ---- row sums (over this wave's 4 col-tiles) ----
  #pragma unroll
  for (int i = 0; i < 4; ++i) {
    #pragma unroll
    for (int r = 0; r < 4; ++r) {
      float rs = acc[i][0][r] + acc[i][1][r] + acc[i][2][r] + acc[i][3][r];
      rs += __shfl_xor(rs, 1); rs += __shfl_xor(rs, 2);
      rs += __shfl_xor(rs, 4); rs += __shfl_xor(rs, 8);
      if (fr == 0) wsA[cb][rb*64 + i*16 + fq*4 + r] = rs;
    }
  }
  // ---- col sums (over this wave's 4 row-tiles) ----
  #pragma unroll
  for (int j = 0; j < 4; ++j) {
    float cs = 0.f;
    #pragma unroll
    for (int i = 0; i < 4; ++i)
      #pragma unroll
      for (int r = 0; r < 4; ++r) cs += acc[i][j][r];
    cs += __shfl_xor(cs, 16); cs += __shfl_xor(cs, 32);
    if (fq == 0) wtA[rb][cb*64 + j*16 + fr] = cs;
  }

  // ---- border exps + sums ----
  const float pbt = (tid < 129) ? exp2f((btv - mraw) * SCLG2E) : 0.f;
  const float pbs = (tid < 128) ? exp2f((bsv - mraw) * SCLG2E) : 0.f;
  float sbt = pbt, sbs = pbs;
  #pragma unroll
  for (int off = 32; off > 0; off >>= 1) {
    sbt += __shfl_xor(sbt, off);
    sbs += __shfl_xor(sbs, off);
  }
  if (lane == 0) { redD[w] = sbt; redE[w] = sbs; }
  if (tid == 128) cornerP = pbt;
  __syncthreads();

  const float pbt_sum = redD[0] + redD[1] + redD[2] + redD[3];
  const float pbs_sum = redE[0] + redE[1] + redE[2] + redE[3];
  const float core_sum = redC[0] + redC[1] + redC[2] + redC[3];
  const float invZ = 1.0f / (core_sum + pbt_sum + pbs_sum);

  if (tid < WPAD) {
    float wsv = (tid < 128) ? (wsA[0][tid] + wsA[1][tid] + pbs)
              : (tid == 128) ? pbt_sum : 0.f;
    float wtv = (tid < 128) ? (wtA[0][tid] + wtA[1][tid] + pbt)
              : (tid == 128) ? (pbs_sum + cornerP) : 0.f;
    wsn[(size_t)gid*WPAD + tid] = (f16)(wsv * invZ);
    wtn[(size_t)gid*WPAD + tid] = (f16)(wtv * invZ);
  }
}

// ---------------------------------------------------------------------------
// ctx GEMM: sctx[l][hd] = sum_s wsn[l][s] * skey[s][hd]  (keyT pre-transposed)
// ---------------------------------------------------------------------------
__global__ __launch_bounds__(256) void ctx_gemm(
    const f16* __restrict__ wsn, const f16* __restrict__ wtn,
    const f16* __restrict__ skeyT, const f16* __restrict__ tkeyT,
    f16* __restrict__ sctx, f16* __restrict__ tctx)
{
  __shared__ __align__(16) f16 As[64*168];
  __shared__ __align__(16) f16 Bs[64*168];
  const int z = blockIdx.x & 1, b = blockIdx.x >> 1;
  const int mt = blockIdx.y, nt = blockIdx.z;
  const int tid = threadIdx.x, lane = tid & 63, w = tid >> 6;
  const int wr = w & 1, wc = w >> 1;
  const int fq = lane >> 4, fr = lane & 15;

  const f16* A  = (z ? wtn : wsn) + ((size_t)b*256 + mt*64)*WPAD;
  const f16* Bt = (z ? tkeyT : skeyT) + ((size_t)b*512 + nt*64)*WPAD;

  for (int t = tid; t < 1280; t += 256) {
    int r = t / 20, c = t % 20;
    *(uint4*)(&As[r*168 + c*8]) = *(const uint4*)(A + (size_t)r*WPAD + c*8);
    *(uint4*)(&Bs[r*168 + c*8]) = *(const uint4*)(Bt + (size_t)r*WPAD + c*8);
  }
  __syncthreads();

  f32x4 acc[2][2] = {};
  #pragma unroll
  for (int ks = 0; ks < 5; ++ks) {
    f16x8 af[2], bf_[2];
    #pragma unroll
    for (int i = 0; i < 2; ++i) {
      af[i]  = *(const f16x8*)(&As[(wr*32 + i*16 + fr)*168 + ks*32 + fq*8]);
      bf_[i] = *(const f16x8*)(&Bs[(wc*32 + i*16 + fr)*168 + ks*32 + fq*8]);
    }
    #pragma unroll
    for (int i = 0; i < 2; ++i)
      #pragma unroll
      for (int j = 0; j < 2; ++j)
        acc[i][j] = __builtin_amdgcn_mfma_f32_16x16x32_f16(af[i], bf_[j], acc[i][j], 0, 0, 0);
  }

  f16* out = z ? tctx : sctx;
  #pragma unroll
  for (int i = 0; i < 2; ++i)
    #pragma unroll
    for (int j = 0; j < 2; ++j) {
      int col = nt*64 + wc*32 + j*16 + fr;
      #pragma unroll
      for (int r = 0; r < 4; ++r) {
        int row = b*256 + mt*64 + wr*32 + i*16 + fq*4 + r;
        out[(size_t)row*HD + col] = (f16)acc[i][j][r];
      }
    }
}

// ---------------------------------------------------------------------------
// out = tanh([query(f32) | sctx | tctx] @ WoT^T + bo), K = 1536, f32 out.
// ---------------------------------------------------------------------------
__global__ __launch_bounds__(256) void gemm_out(
    const float* __restrict__ query, const f16* __restrict__ sctx,
    const f16* __restrict__ tctx, const f16* __restrict__ WoT,
    const float* __restrict__ bias, float* __restrict__ C)
{
  __shared__ __align__(16) f16 As[64*64];
  __shared__ __align__(16) f16 Bs[64*64];
  const int tid  = threadIdx.x;
  const int lane = tid & 63;
  const int w    = tid >> 6;
  const int wr   = w & 1, wc = w >> 1;
  const int fq   = lane >> 4, fr = lane & 15;
  const int bm = blockIdx.x * 64, bn = blockIdx.y * 64;

  f32x4 acc[2][2] = {};

  for (int k0 = 0; k0 < 1536; k0 += 64) {
    const int seg  = k0 >> 9;
    const int kloc = k0 & 511;
    #pragma unroll
    for (int i = 0; i < 2; ++i) {
      int idx = tid + 256*i;
      int r = idx >> 3, c = idx & 7;
      int o = ((r << 7) + (c << 4)) ^ ((r & 7) << 4);
      if (seg == 0) {
        const float* ap = query + (size_t)(bm + r)*512 + kloc + c*8;
        float4 x0 = *(const float4*)ap;
        float4 x1 = *(const float4*)(ap + 4);
        f16x8 va = { (f16)x0.x, (f16)x0.y, (f16)x0.z, (f16)x0.w,
                     (f16)x1.x, (f16)x1.y, (f16)x1.z, (f16)x1.w };
        *(f16x8*)((char*)As + o) = va;
      } else {
        const f16* Ap = (seg == 1) ? sctx : tctx;
        *(uint4*)((char*)As + o) = *(const uint4*)(Ap + (size_t)(bm + r)*512 + kloc + c*8);
      }
      *(uint4*)((char*)Bs + o) = *(const uint4*)(WoT + (size_t)(bn + r)*1536 + k0 + c*8);
    }
    __syncthreads();
    #pragma unroll
    for (int ks = 0; ks < 2; ++ks) {
      f16x8 af[2], bf_[2];
      #pragma unroll
      for (int i = 0; i < 2; ++i) {
        int ra = wr*32 + i*16 + fr;
        int oa = ((ra << 7) + (ks << 6) + (fq << 4)) ^ ((ra & 7) << 4);
        af[i] = *(const f16x8*)((const char*)As + oa);
        int rb = wc*32 + i*16 + fr;
        int ob = ((rb << 7) + (ks << 6) + (fq << 4)) ^ ((rb & 7) << 4);
        bf_[i] = *(const f16x8*)((const char*)Bs + ob);
      }
      #pragma unroll
      for (int i = 0; i < 2; ++i)
        #pragma unroll
        for (int j = 0; j < 2; ++j)
          acc[i][j] = __builtin_amdgcn_mfma_f32_16x16x32_f16(af[i], bf_[j], acc[i][j], 0, 0, 0);
    }
    __syncthreads();
  }

  #pragma unroll
  for (int i = 0; i < 2; ++i)
    #pragma unroll
    for (int j = 0; j < 2; ++j) {
      int n = bn + wc*32 + j*16 + fr;
      float bv = bias[n];
      #pragma unroll
      for (int r = 0; r < 4; ++r) {
        int m = bm + wr*32 + i*16 + fq*4 + r;
        float xx = acc[i][j][r] + bv;
        xx = fminf(fmaxf(xx, -20.f), 20.f);
        float e = exp2f(TANH2E * xx);
        C[(size_t)m*HD + n] = (e - 1.0f) / (e + 1.0f);
      }
    }
}

extern "C" void kernel_launch(void* const* d_in, const int* in_sizes, int n_in,
                              void* d_out, int out_size, void* d_ws, size_t ws_size,
                              hipStream_t stream) {
  (void)in_sizes; (void)n_in; (void)out_size; (void)ws_size;
  const float* query = (const float*)d_in[0];
  const float* src   = (const float*)d_in[1];
  const float* trg   = (const float*)d_in[2];
  const float* Wq    = (const float*)d_in[3];
  const float* bq    = (const float*)d_in[4];
  const float* Wsm   = (const float*)d_in[5];
  const float* bs    = (const float*)d_in[6];
  const float* Wtm   = (const float*)d_in[7];
  const float* bt    = (const float*)d_in[8];
  const float* Wo    = (const float*)d_in[9];
  const float* bo    = (const float*)d_in[10];
  float* out = (float*)d_out;

  // workspace layout (~32 MB)
  char* p = (char*)d_ws;
  f16* WqT   = (f16*)p;  p += (size_t)HD*HD*2;
  f16* WsT   = (f16*)p;  p += (size_t)HD*HD*2;
  f16* WtT   = (f16*)p;  p += (size_t)HD*HD*2;
  f16* WoT   = (f16*)p;  p += (size_t)1536*HD*2;
  f16* q_h   = (f16*)p;  p += (size_t)MQ*HD*2;
  f16* skey  = (f16*)p;  p += (size_t)NBATCH*RPAD*HD*2;
  f16* tkey  = (f16*)p;  p += (size_t)NBATCH*RPAD*HD*2;
  f16* skeyT = (f16*)p;  p += (size_t)NBATCH*HD*WPAD*2;
  f16* tkeyT = (f16*)p;  p += (size_t)NBATCH*HD*WPAD*2;
  f16* wsn   = (f16*)p;  p += (size_t)MQ*WPAD*2;
  f16* wtn   = (f16*)p;  p += (size_t)MQ*WPAD*2;
  f16* sctx  = (f16*)p;  p += (size_t)MQ*HD*2;
  f16* tctx  = (f16*)p;  p += (size_t)MQ*HD*2;
  float* Sb  = (float*)p; p += (size_t)2*MQ*RPAD*4;

  dim3 blk(256);
  prep_kernel<<<dim3(416), blk, 0, stream>>>(Wq, Wsm, Wtm, Wo, bs, bt,
                                             WqT, WsT, WtT, WoT,
                                             skey, tkey, skeyT, tkeyT);
  gemm_in<<<dim3(128, 8), blk, 0, stream>>>(query, src, trg, WqT, WsT, WtT,
                                            bq, bs, bt, q_h, skey, tkey,
                                            skeyT, tkeyT);
  border_kernel<<<dim3(256), blk, 0, stream>>>(q_h, skey, tkey, Sb);
  attn_core<<<dim3(MQ), blk, 0, stream>>>(q_h, skey, tkey, Sb, wsn, wtn);
  ctx_gemm<<<dim3(32, 4, 8), blk, 0, stream>>>(wsn, wtn, skeyT, tkeyT, sctx, tctx);
  gemm_out<<<dim3(64, 8), blk, 0, stream>>>(query, sctx, tctx, WoT, bo, out);
}